// Round 7
// baseline (6965.336 us; speedup 1.0000x reference)
//
#include <hip/hip_runtime.h>
#include <hip/hip_bf16.h>
#include <stdint.h>
#include <stddef.h>

// Problem constants
#define B_   4096
#define H_   1024
#define L_   256
#define C_   128
#define T_   64
#define H3_  3072

typedef unsigned short u16;
typedef __attribute__((ext_vector_type(8))) short bf16x8;   // 8 bf16 = 4 VGPRs
typedef __attribute__((ext_vector_type(4))) float f32x4;

typedef const void __attribute__((address_space(1)))* as1_cvp;
typedef void __attribute__((address_space(3)))* as3_vp;

__device__ __forceinline__ void gl2lds16(const void* g, void* l) {
  __builtin_amdgcn_global_load_lds((as1_cvp)g, (as3_vp)l, 16, 0, 0);
}

__device__ __forceinline__ float bf2f(u16 u) {
  union { float f; unsigned int i; } x; x.i = ((unsigned int)u) << 16; return x.f;
}
__device__ __forceinline__ u16 f2bf(float f) {
  union { float f; unsigned int i; } x; x.f = f;
  unsigned int r = x.i + 0x7fffu + ((x.i >> 16) & 1u);  // RNE
  return (u16)(r >> 16);
}
__device__ __forceinline__ float sigm(float x) { return 1.f / (1.f + __expf(-x)); }
__device__ __forceinline__ float tanh_fast(float x) {
  float e = __expf(2.f * x); return 1.f - 2.f / (e + 1.f);
}

// ---------------------------------------------------------------------------
// 128x128-tile bf16 GEMM body (m97 structure) — per-call precompute GEMMs only.
// ---------------------------------------------------------------------------
template<int OUT_MODE>
__device__ __forceinline__ void gemm_tile_body(
    u16* As, u16* Ws,
    const u16* __restrict__ A, int lda,
    const u16* __restrict__ W, int ldw,
    const float* __restrict__ bias,
    void* __restrict__ C0p, void* __restrict__ C1p, int ldc, int K,
    int m0, int n0)
{
  const int tid  = threadIdx.x;
  const int wave = tid >> 6, lane = tid & 63;
  const int wm = (wave >> 1) * 64, wn = (wave & 1) * 64;
  const int lrow = lane & 15, lq = lane >> 4;
  const int arow = wave * 8 + (lane >> 3);
  const int acol = (lane & 7) * 8;

  f32x4 acc[4][4] = {};

  const u16* Ag = A + (size_t)m0 * lda;
  const u16* Wg = W + (size_t)n0 * ldw;

  for (int k0 = 0; k0 < K; k0 += 64) {
    __syncthreads();
    #pragma unroll
    for (int rd = 0; rd < 4; rd++) {
      gl2lds16(Ag + (size_t)(rd * 32 + arow) * lda + (k0 + acol), As + rd * 2048 + wave * 512);
      gl2lds16(Wg + (size_t)(rd * 32 + arow) * ldw + (k0 + acol), Ws + rd * 2048 + wave * 512);
    }
    __syncthreads();
    #pragma unroll
    for (int kk = 0; kk < 64; kk += 32) {
      bf16x8 af[4], bw[4];
      #pragma unroll
      for (int i = 0; i < 4; i++)
        af[i] = *(const bf16x8*)&As[(wm + i * 16 + lrow) * 64 + kk + lq * 8];
      #pragma unroll
      for (int j = 0; j < 4; j++)
        bw[j] = *(const bf16x8*)&Ws[(wn + j * 16 + lrow) * 64 + kk + lq * 8];
      #pragma unroll
      for (int i = 0; i < 4; i++)
        #pragma unroll
        for (int j = 0; j < 4; j++)
          acc[i][j] = __builtin_amdgcn_mfma_f32_16x16x32_bf16(af[i], bw[j], acc[i][j], 0, 0, 0);
    }
  }

  #pragma unroll
  for (int j = 0; j < 4; j++) {
    const int col = n0 + wn + j * 16 + lrow;
    const float bv = bias ? bias[col] : 0.f;
    #pragma unroll
    for (int i = 0; i < 4; i++) {
      #pragma unroll
      for (int r = 0; r < 4; r++) {
        const int row = m0 + wm + i * 16 + lq * 4 + r;
        float v = acc[i][j][r] + bv;
        if (OUT_MODE == 0) {
          ((float*)C0p)[(size_t)row * ldc + col] = v;
        } else if (OUT_MODE == 1) {
          ((u16*)C0p)[(size_t)row * ldc + col] = f2bf(v);
        } else {
          u16 hv = f2bf(v);
          ((u16*)C0p)[(size_t)row * ldc + col] = hv;
          ((u16*)C1p)[(size_t)row * ldc + col] = hv;
        }
      }
    }
  }
}

template<int OUT_MODE>
__global__ __launch_bounds__(256) void gemm_bt(
    const u16* __restrict__ A, int lda,
    const u16* __restrict__ W, int ldw,
    const float* __restrict__ bias,
    void* __restrict__ C0p, void* __restrict__ C1p, int ldc, int K)
{
  __shared__ __align__(16) u16 As[128 * 64];
  __shared__ __align__(16) u16 Ws[128 * 64];
  gemm_tile_body<OUT_MODE>(As, Ws, A, lda, W, ldw, bias, C0p, C1p, ldc, K,
                           blockIdx.y * 128, blockIdx.x * 128);
}

// ---------------------------------------------------------------------------
// out = h2 @ Wo^T + Oz; writes d_out[:,t,:], per-row argmax -> cnew.
// 2-deep counted-vmcnt pipeline + st_16x32 swizzle (proven in round 6).
// ---------------------------------------------------------------------------
#define OA_TSZ 4096   // 64x64 u16
#define OW_TSZ 8192   // 128x64 u16

__device__ __forceinline__ void o_stage(const u16* h2, const u16* Wo,
                                        int b0, int k0, u16* bA, u16* bW) {
  const int tid = threadIdx.x, wave = tid >> 6, lane = tid & 63;
  const int arow = wave * 8 + (lane >> 3);
  const int cSw = (((lane & 7) ^ ((lane >> 5) << 1)) << 3);
  #pragma unroll
  for (int rd = 0; rd < 2; rd++)
    gl2lds16(h2 + (size_t)(b0 + rd * 32 + arow) * H_ + k0 + cSw, bA + rd * 2048 + wave * 512);
  #pragma unroll
  for (int rd = 0; rd < 4; rd++)
    gl2lds16(Wo + (size_t)(rd * 32 + arow) * H_ + k0 + cSw, bW + rd * 2048 + wave * 512);
}

__device__ __forceinline__ void out_body(
    u16* As, u16* Ws, int ob,
    const u16* __restrict__ h2, const u16* __restrict__ Wo,
    const float* __restrict__ Oz, float* __restrict__ outp,
    int* __restrict__ cnew, int t)
{
  const int tid = threadIdx.x, wave = tid >> 6, lane = tid & 63;
  const int b0 = ob * 64;
  const int lrow = lane & 15, lq = lane >> 4;
  const int rsw = ((lrow >> 2) & 1) << 4;
  f32x4 acc[8] = {};

  o_stage(h2, Wo, b0, 0, As, Ws);
  o_stage(h2, Wo, b0, 64, As + OA_TSZ, Ws + OW_TSZ);

  #pragma unroll 1
  for (int v = 0; v < 16; v++) {
    u16* bA = (v & 1) ? As + OA_TSZ : As;
    u16* bW = (v & 1) ? Ws + OW_TSZ : Ws;
    if (v + 1 < 16) asm volatile("s_waitcnt vmcnt(6)" ::: "memory");
    else            asm volatile("s_waitcnt vmcnt(0)" ::: "memory");
    __builtin_amdgcn_sched_barrier(0);
    __builtin_amdgcn_s_barrier();
    __builtin_amdgcn_sched_barrier(0);
    #pragma unroll
    for (int kk = 0; kk < 64; kk += 32) {
      const int c = (kk + lq * 8) ^ rsw;
      bf16x8 af = *(const bf16x8*)&bA[(wave * 16 + lrow) * 64 + c];
      #pragma unroll
      for (int j = 0; j < 8; j++) {
        bf16x8 bw = *(const bf16x8*)&bW[(j * 16 + lrow) * 64 + c];
        acc[j] = __builtin_amdgcn_mfma_f32_16x16x32_bf16(af, bw, acc[j], 0, 0, 0);
      }
    }
    __builtin_amdgcn_sched_barrier(0);
    __builtin_amdgcn_s_barrier();
    __builtin_amdgcn_sched_barrier(0);
    if (v + 2 < 16) o_stage(h2, Wo, b0, (v + 2) * 64, bA, bW);
  }

  #pragma unroll
  for (int r = 0; r < 4; r++) {
    const int row = b0 + wave * 16 + lq * 4 + r;
    float mv = -3.4e38f; int mi = 0;
    #pragma unroll
    for (int j = 0; j < 8; j++) {
      const int col = j * 16 + lrow;
      float v = acc[j][r] + Oz[(size_t)row * C_ + col];
      outp[(size_t)row * (T_ * C_) + t * C_ + col] = v;
      if (v > mv) { mv = v; mi = col; }
    }
    #pragma unroll
    for (int off = 1; off < 16; off <<= 1) {
      float ov = __shfl_xor(mv, off);
      int   oi = __shfl_xor(mi, off);
      if (ov > mv || (ov == mv && oi < mi)) { mv = ov; mi = oi; }
    }
    if (lrow == 0) cnew[row] = mi;
  }
}

__global__ __launch_bounds__(256) void out_k(
    const u16* __restrict__ h2cur, const u16* __restrict__ Wo,
    const float* __restrict__ Oz, float* __restrict__ outp,
    int* __restrict__ cbuf, int t)
{
  __shared__ __align__(16) u16 As[2 * OA_TSZ];
  __shared__ __align__(16) u16 Ws[2 * OW_TSZ];
  out_body(As, Ws, blockIdx.x, h2cur, Wo, Oz, outp, cbuf, t);
}

// ===========================================================================
// 256-row x 64-j x 3-gate fused GRU GEMM — phase-interleaved schedule.
// Round-7 change (single delta vs round 6): ONE-PHASE-AHEAD ds_read
// pipelining with COUNTED lgkm waits. Reads for phase p+1 are issued before
// phase p's MFMA (source buffers are stable across the intra-tile barriers —
// stages write only other buffers), so each phase's read latency hides under
// the previous phase's MFMA:
//   head: reads P0 (8) + reads P1 (8) -> lgkmcnt(8) -> MFMA0
//   then: reads P2 (4)                -> lgkmcnt(4) -> MFMA1
//   then:                               lgkmcnt(0) -> MFMA2
// Only +1 phase of operand registers (~+32-48 VGPR) — the bounded version of
// round 5's failed whole-tile hoist (+80 VGPR). Rule-18: every counted-wait
// asm is immediately followed by sched_barrier(0).
// Stage issue / vmcnt schedule unchanged (A 3-deep, W 2-deep, head vmcnt(4)).
// ===========================================================================

#define A_TSZ 16384   // 256x64 u16
#define W_TSZ 12288   // 192x64 u16

__device__ __forceinline__ void stageA_lo(const u16* Ag, int k0, u16* bA) {
  const int tid = threadIdx.x, wave = tid >> 6, lane = tid & 63;
  const int r64 = wave * 8 + (lane >> 3);
  const int cSw = (((lane & 7) ^ ((lane >> 5) << 1)) << 3);
  gl2lds16(Ag + (size_t)(r64) * H_ + k0 + cSw, bA + wave * 512);
  gl2lds16(Ag + (size_t)(64 + r64) * H_ + k0 + cSw, bA + 4096 + wave * 512);
}
__device__ __forceinline__ void stageA_hi(const u16* Ag, int k0, u16* bA) {
  const int tid = threadIdx.x, wave = tid >> 6, lane = tid & 63;
  const int r64 = wave * 8 + (lane >> 3);
  const int cSw = (((lane & 7) ^ ((lane >> 5) << 1)) << 3);
  gl2lds16(Ag + (size_t)(128 + r64) * H_ + k0 + cSw, bA + 8192 + wave * 512);
  gl2lds16(Ag + (size_t)(192 + r64) * H_ + k0 + cSw, bA + 12288 + wave * 512);
}
__device__ __forceinline__ void stageW(const u16* Wg, int k0, u16* bW) {
  const int tid = threadIdx.x, wave = tid >> 6, lane = tid & 63;
  const int r64 = wave * 8 + (lane >> 3);
  const int cSw = (((lane & 7) ^ ((lane >> 5) << 1)) << 3);
  #pragma unroll
  for (int rd = 0; rd < 3; rd++)
    gl2lds16(Wg + (size_t)(rd * 1024 + r64) * H_ + k0 + cSw, bW + rd * 4096 + wave * 512);
}

// Phase p reads (LDS -> regs). Phase MFMA groups (16 each):
//   P0: {g0,g1}@kk0   P1: {g2}@kk0 + {g0}@kk32   P2: {g1,g2}@kk32
template<int PHASE>
__device__ __forceinline__ void phase_reads(const u16* bA, const u16* bW,
    bf16x8 af0[4], bf16x8 af1[4], bf16x8 bwv[2][2])
{
  const int tid = threadIdx.x, wave = tid >> 6, lane = tid & 63;
  const int wmh = wave >> 1, wj = wave & 1;
  const int lrow = lane & 15, lq = lane >> 4;
  const int rsw = ((lrow >> 2) & 1) << 4;
  const int c0 = (lq * 8) ^ rsw;
  const int c1 = (32 + lq * 8) ^ rsw;
  if (PHASE == 0) {
    #pragma unroll
    for (int i = 0; i < 4; i++)
      af0[i] = *(const bf16x8*)&bA[(wmh * 64 + i * 16 + lrow) * 64 + c0];
    #pragma unroll
    for (int u = 0; u < 2; u++) {
      bwv[0][u] = *(const bf16x8*)&bW[(wj * 32 + u * 16 + lrow) * 64 + c0];
      bwv[1][u] = *(const bf16x8*)&bW[(64 + wj * 32 + u * 16 + lrow) * 64 + c0];
    }
  } else if (PHASE == 1) {
    #pragma unroll
    for (int i = 0; i < 4; i++)
      af1[i] = *(const bf16x8*)&bA[(wmh * 64 + i * 16 + lrow) * 64 + c1];
    #pragma unroll
    for (int u = 0; u < 2; u++) {
      bwv[0][u] = *(const bf16x8*)&bW[(128 + wj * 32 + u * 16 + lrow) * 64 + c0];
      bwv[1][u] = *(const bf16x8*)&bW[(wj * 32 + u * 16 + lrow) * 64 + c1];
    }
  } else {
    #pragma unroll
    for (int u = 0; u < 2; u++) {
      bwv[0][u] = *(const bf16x8*)&bW[(64 + wj * 32 + u * 16 + lrow) * 64 + c1];
      bwv[1][u] = *(const bf16x8*)&bW[(128 + wj * 32 + u * 16 + lrow) * 64 + c1];
    }
  }
}

template<int PHASE, bool PH2v>
__device__ __forceinline__ void phase_fma(const bf16x8 bwv[2][2],
    const bf16x8 af0[4], const bf16x8 af1[4],
    f32x4 acc[3][2][4], f32x4 accN[2][4])
{
  if (PHASE == 0) {
    #pragma unroll
    for (int u = 0; u < 2; u++)
      #pragma unroll
      for (int i = 0; i < 4; i++) {
        acc[0][u][i] = __builtin_amdgcn_mfma_f32_16x16x32_bf16(af0[i], bwv[0][u], acc[0][u][i], 0, 0, 0);
        acc[1][u][i] = __builtin_amdgcn_mfma_f32_16x16x32_bf16(af0[i], bwv[1][u], acc[1][u][i], 0, 0, 0);
      }
  } else if (PHASE == 1) {
    #pragma unroll
    for (int u = 0; u < 2; u++)
      #pragma unroll
      for (int i = 0; i < 4; i++) {
        if (PH2v)
          accN[u][i] = __builtin_amdgcn_mfma_f32_16x16x32_bf16(af0[i], bwv[0][u], accN[u][i], 0, 0, 0);
        else
          acc[2][u][i] = __builtin_amdgcn_mfma_f32_16x16x32_bf16(af0[i], bwv[0][u], acc[2][u][i], 0, 0, 0);
        acc[0][u][i] = __builtin_amdgcn_mfma_f32_16x16x32_bf16(af1[i], bwv[1][u], acc[0][u][i], 0, 0, 0);
      }
  } else {
    #pragma unroll
    for (int u = 0; u < 2; u++)
      #pragma unroll
      for (int i = 0; i < 4; i++) {
        acc[1][u][i] = __builtin_amdgcn_mfma_f32_16x16x32_bf16(af1[i], bwv[0][u], acc[1][u][i], 0, 0, 0);
        if (PH2v)
          accN[u][i] = __builtin_amdgcn_mfma_f32_16x16x32_bf16(af1[i], bwv[1][u], accN[u][i], 0, 0, 0);
        else
          acc[2][u][i] = __builtin_amdgcn_mfma_f32_16x16x32_bf16(af1[i], bwv[1][u], acc[2][u][i], 0, 0, 0);
      }
  }
}

// One 64-K tile with one-phase-ahead read pipelining (see header comment).
template<int NT1, int NT2, bool PH2v>
__device__ __forceinline__ void tile8(
    int v, u16* aC, u16* wC, u16* wN, u16* aN2,
    const u16* A1g, const u16* W1g, const u16* A2g, const u16* W2g,
    f32x4 acc[3][2][4], f32x4 accN[2][4])
{
  constexpr int NT = NT1 + NT2;
  if (v + 1 < NT) asm volatile("s_waitcnt vmcnt(4)" ::: "memory");
  else            asm volatile("s_waitcnt vmcnt(0)" ::: "memory");
  __builtin_amdgcn_sched_barrier(0);
  __builtin_amdgcn_s_barrier();
  __builtin_amdgcn_sched_barrier(0);

  bf16x8 af0[4], af1[4], bw0[2][2], bw1[2][2], bw2[2][2];

  // ---- P0: issue reads for P0 AND P1, wait only for P0's (8 remain) ----
  phase_reads<0>(aC, wC, af0, af1, bw0);
  phase_reads<1>(aC, wC, af0, af1, bw1);
  __builtin_amdgcn_sched_barrier(0);
  {
    const int w = v + 1;
    if (w < NT) stageW((w < NT1) ? W1g : W2g, ((w < NT1) ? w : w - NT1) * 64, wN);
  }
  asm volatile("s_waitcnt lgkmcnt(8)" ::: "memory");
  __builtin_amdgcn_sched_barrier(0);
  __builtin_amdgcn_s_setprio(1);
  phase_fma<0, PH2v>(bw0, af0, af1, acc, accN);
  __builtin_amdgcn_s_setprio(0);
  __builtin_amdgcn_sched_barrier(0);
  __builtin_amdgcn_s_barrier();
  __builtin_amdgcn_sched_barrier(0);

  // ---- P1: issue reads for P2, wait for P1's (4 remain) ----
  phase_reads<2>(aC, wC, af0, af1, bw2);
  __builtin_amdgcn_sched_barrier(0);
  {
    const int w = v + 2;
    if (w < NT) stageA_lo((w < NT1) ? A1g : A2g, ((w < NT1) ? w : w - NT1) * 64, aN2);
  }
  asm volatile("s_waitcnt lgkmcnt(4)" ::: "memory");
  __builtin_amdgcn_sched_barrier(0);
  __builtin_amdgcn_s_setprio(1);
  phase_fma<1, PH2v>(bw1, af0, af1, acc, accN);
  __builtin_amdgcn_s_setprio(0);
  __builtin_amdgcn_sched_barrier(0);
  __builtin_amdgcn_s_barrier();
  __builtin_amdgcn_sched_barrier(0);

  // ---- P2 ----
  {
    const int w = v + 2;
    if (w < NT) stageA_hi((w < NT1) ? A1g : A2g, ((w < NT1) ? w : w - NT1) * 64, aN2);
  }
  asm volatile("s_waitcnt lgkmcnt(0)" ::: "memory");
  __builtin_amdgcn_sched_barrier(0);
  __builtin_amdgcn_s_setprio(1);
  phase_fma<2, PH2v>(bw2, af0, af1, acc, accN);
  __builtin_amdgcn_s_setprio(0);
  __builtin_amdgcn_sched_barrier(0);
}

template<int NT1, int NT2>
__device__ __forceinline__ void kloop8(
    u16* As, u16* Ws,
    const u16* A1g, const u16* W1g, const u16* A2g, const u16* W2g,
    f32x4 acc[3][2][4], f32x4 accN[2][4])
{
  constexpr int NT = NT1 + NT2;
  u16* aB0 = As; u16* aB1 = As + A_TSZ; u16* aB2 = As + 2 * A_TSZ;
  u16* wB0 = Ws; u16* wB1 = Ws + W_TSZ;

  // prologue issue order matters for vmcnt: A(0) [4], W(0) [3], A(1) [4]
  stageA_lo(A1g, 0, aB0); stageA_hi(A1g, 0, aB0);
  stageW(W1g, 0, wB0);
  if (NT > 1) {
    const u16* Ag = (1 < NT1) ? A1g : A2g;
    const int k0 = (1 < NT1) ? 64 : 0;
    stageA_lo(Ag, k0, aB1); stageA_hi(Ag, k0, aB1);
  }

  u16* aC = aB0; u16* aN1 = aB1; u16* aN2 = aB2;
  u16* wC = wB0; u16* wN = wB1;

  #pragma unroll 1
  for (int v = 0; v < NT1; v++) {
    tile8<NT1, NT2, false>(v, aC, wC, wN, aN2, A1g, W1g, A2g, W2g, acc, accN);
    u16* t = aC; aC = aN1; aN1 = aN2; aN2 = t;
    u16* tw = wC; wC = wN; wN = tw;
  }
  #pragma unroll 1
  for (int v = NT1; v < NT; v++) {
    tile8<NT1, NT2, true>(v, aC, wC, wN, aN2, A1g, W1g, A2g, W2g, acc, accN);
    u16* t = aC; aC = aN1; aN1 = aN2; aN2 = t;
    u16* tw = wC; wC = wN; wN = tw;
  }
}

// Layer-0 fused: gh0 GEMM + GRU cell0 epilogue (Egi gather + Gz + h1 update).
__global__ __launch_bounds__(512, 2) void gru0_256(
    const u16* __restrict__ h1old, const u16* __restrict__ whh0,
    const float* __restrict__ b_hh0, const int* __restrict__ cbuf,
    const u16* __restrict__ Egi, const u16* __restrict__ Gz,
    u16* __restrict__ h1new)
{
  __shared__ __align__(16) u16 As[3 * A_TSZ];
  __shared__ __align__(16) u16 Ws[2 * W_TSZ];
  const int bid = blockIdx.x;
  const int xcd = bid & 7, k = bid >> 3;   // k: 0..31
  const int jt = xcd * 2 + (k & 1);        // 0..15
  const int m  = k >> 1;                   // 0..15
  const int m0 = m * 256, j0 = jt * 64;

  f32x4 acc[3][2][4] = {};
  f32x4 accN[2][4] = {};
  kloop8<16, 0>(As, Ws,
                h1old + (size_t)m0 * H_, whh0 + (size_t)j0 * H_,
                h1old + (size_t)m0 * H_, whh0 + (size_t)j0 * H_,
                acc, accN);

  const int tid = threadIdx.x, wave = tid >> 6, lane = tid & 63;
  const int wmh = wave >> 1, wj = wave & 1;
  const int lrow = lane & 15, lq = lane >> 4;

  #pragma unroll
  for (int u = 0; u < 2; u++) {
    const int j = j0 + wj * 32 + u * 16 + lrow;
    const float bR = b_hh0[j];
    const float bZ = b_hh0[H_ + j];
    const float bN = b_hh0[2 * H_ + j];
    #pragma unroll
    for (int i = 0; i < 4; i++) {
      #pragma unroll
      for (int rr = 0; rr < 4; rr++) {
        const int row = m0 + wmh * 64 + i * 16 + lq * 4 + rr;
        const size_t eb = (size_t)cbuf[row] * H3_ + j;
        const size_t gb = (size_t)row * H3_ + j;
        float r  = sigm(bf2f(Egi[eb])           + bf2f(Gz[gb])           + acc[0][u][i][rr] + bR);
        float zg = sigm(bf2f(Egi[eb + H_])      + bf2f(Gz[gb + H_])      + acc[1][u][i][rr] + bZ);
        float nn = tanh_fast(bf2f(Egi[eb + 2 * H_]) + bf2f(Gz[gb + 2 * H_])
                             + r * (acc[2][u][i][rr] + bN));
        float hold = bf2f(h1old[(size_t)row * H_ + j]);
        h1new[(size_t)row * H_ + j] = f2bf((1.f - zg) * nn + zg * hold);
      }
    }
  }
}

// Layer-1 fused: dual GEMM (gi1 = h1@wih1^T tiles 0..15, gh1 = h2old@whh1^T
// tiles 16..31; r/z shared accumulators, n separate) + GRU cell1 -> h2new.
__global__ __launch_bounds__(512, 2) void gru1_256(
    const u16* __restrict__ h1, const u16* __restrict__ h2old,
    const u16* __restrict__ wih1, const u16* __restrict__ whh1,
    const float* __restrict__ b_ih1, const float* __restrict__ b_hh1,
    u16* __restrict__ h2new)
{
  __shared__ __align__(16) u16 As[3 * A_TSZ];
  __shared__ __align__(16) u16 Ws[2 * W_TSZ];
  const int bid = blockIdx.x;
  const int xcd = bid & 7, k = bid >> 3;
  const int jt = xcd * 2 + (k & 1);
  const int m  = k >> 1;
  const int m0 = m * 256, j0 = jt * 64;

  f32x4 acc[3][2][4] = {};
  f32x4 accN[2][4] = {};
  kloop8<16, 16>(As, Ws,
                 h1    + (size_t)m0 * H_, wih1 + (size_t)j0 * H_,
                 h2old + (size_t)m0 * H_, whh1 + (size_t)j0 * H_,
                 acc, accN);

  const int tid = threadIdx.x, wave = tid >> 6, lane = tid & 63;
  const int wmh = wave >> 1, wj = wave & 1;
  const int lrow = lane & 15, lq = lane >> 4;

  #pragma unroll
  for (int u = 0; u < 2; u++) {
    const int j = j0 + wj * 32 + u * 16 + lrow;
    const float bR  = b_ih1[j] + b_hh1[j];
    const float bZ  = b_ih1[H_ + j] + b_hh1[H_ + j];
    const float bNi = b_ih1[2 * H_ + j];
    const float bNh = b_hh1[2 * H_ + j];
    #pragma unroll
    for (int i = 0; i < 4; i++) {
      #pragma unroll
      for (int rr = 0; rr < 4; rr++) {
        const int row = m0 + wmh * 64 + i * 16 + lq * 4 + rr;
        float r  = sigm(acc[0][u][i][rr] + bR);
        float zg = sigm(acc[1][u][i][rr] + bZ);
        float nn = tanh_fast(acc[2][u][i][rr] + bNi + r * (accN[u][i][rr] + bNh));
        float hold = bf2f(h2old[(size_t)row * H_ + j]);
        h2new[(size_t)row * H_ + j] = f2bf((1.f - zg) * nn + zg * hold);
      }
    }
  }
}

// --------------------------- conversion kernels ----------------------------
__global__ __launch_bounds__(256) void conv_bf16_k(const float* __restrict__ s, u16* __restrict__ d, int n) {
  int i = blockIdx.x * 256 + threadIdx.x;
  if (i < n) d[i] = f2bf(s[i]);
}
__global__ __launch_bounds__(256) void conv_split_k(const float* __restrict__ s, u16* __restrict__ dA,
                                                    u16* __restrict__ dZ, int rows) {
  int i = blockIdx.x * 256 + threadIdx.x;
  if (i >= rows * 1280) return;
  int rr = i / 1280, col = i - rr * 1280;
  float v = s[i];
  if (col < 1024) dA[(size_t)rr * 1024 + col] = f2bf(v);
  else            dZ[(size_t)rr * 256 + (col - 1024)] = f2bf(v);
}
__global__ __launch_bounds__(256) void conv_swish_k(const float* __restrict__ s, u16* __restrict__ d, int n) {
  int i = blockIdx.x * 256 + threadIdx.x;
  if (i < n) { float e = s[i]; d[i] = f2bf(e * sigm(e)); }
}

// ---------------------------------------------------------------------------
static inline char* wsal(char*& p, size_t bytes) {
  char* r = p; p += (bytes + 255) & ~(size_t)255; return r;
}

extern "C" void kernel_launch(void* const* d_in, const int* in_sizes, int n_in,
                              void* d_out, int out_size, void* d_ws, size_t ws_size,
                              hipStream_t stream) {
  const float* z       = (const float*)d_in[0];
  const float* embed_w = (const float*)d_in[1];
  const float* z2h_w   = (const float*)d_in[2];
  const float* z2h_b   = (const float*)d_in[3];
  const float* w_ih0   = (const float*)d_in[4];
  const float* w_hh0   = (const float*)d_in[5];
  const float* b_ih0   = (const float*)d_in[6];
  const float* b_hh0   = (const float*)d_in[7];
  const float* w_ih1   = (const float*)d_in[8];
  const float* w_hh1   = (const float*)d_in[9];
  const float* b_ih1   = (const float*)d_in[10];
  const float* b_hh1   = (const float*)d_in[11];
  const float* h2o_w   = (const float*)d_in[12];
  const float* h2o_b   = (const float*)d_in[13];
  float* outp = (float*)d_out;

  char* p = (char*)d_ws;
  u16* whh0  = (u16*)wsal(p, (size_t)H3_ * H_ * 2);
  u16* wih1  = (u16*)wsal(p, (size_t)H3_ * H_ * 2);
  u16* whh1  = (u16*)wsal(p, (size_t)H3_ * H_ * 2);
  u16* wih0a = (u16*)wsal(p, (size_t)H3_ * H_ * 2);
  u16* wih0z = (u16*)wsal(p, (size_t)H3_ * L_ * 2);
  u16* h2oa  = (u16*)wsal(p, (size_t)C_ * H_ * 2);
  u16* h2oz  = (u16*)wsal(p, (size_t)C_ * L_ * 2);
  u16* z2hb  = (u16*)wsal(p, (size_t)H_ * L_ * 2);
  u16* zb    = (u16*)wsal(p, (size_t)B_ * L_ * 2);
  u16* swe   = (u16*)wsal(p, (size_t)C_ * H_ * 2);
  u16* EgiB  = (u16*)wsal(p, (size_t)C_ * H3_ * 2);
  u16* Gz    = (u16*)wsal(p, (size_t)B_ * H3_ * 2);
  float* Oz  = (float*)wsal(p, (size_t)B_ * C_ * 4);
  u16* h1a   = (u16*)wsal(p, (size_t)B_ * H_ * 2);
  u16* h1b   = (u16*)wsal(p, (size_t)B_ * H_ * 2);
  u16* h2a   = (u16*)wsal(p, (size_t)B_ * H_ * 2);
  u16* h2b   = (u16*)wsal(p, (size_t)B_ * H_ * 2);
  int* cbuf  = (int*)wsal(p, (size_t)B_ * 4);

  // ---- one-time (per call) precompute ----
  conv_bf16_k<<<(B_*L_ + 255)/256, 256, 0, stream>>>(z, zb, B_*L_);
  conv_bf16_k<<<(H_*L_ + 255)/256, 256, 0, stream>>>(z2h_w, z2hb, H_*L_);
  conv_bf16_k<<<(H3_*H_ + 255)/256, 256, 0, stream>>>(w_hh0, whh0, H3_*H_);
  conv_bf16_k<<<(H3_*H_ + 255)/256, 256, 0, stream>>>(w_ih1, wih1, H3_*H_);
  conv_bf16_k<<<(H3_*H_ + 255)/256, 256, 0, stream>>>(w_hh1, whh1, H3_*H_);
  conv_split_k<<<(H3_*1280 + 255)/256, 256, 0, stream>>>(w_ih0, wih0a, wih0z, H3_);
  conv_split_k<<<(C_*1280 + 255)/256, 256, 0, stream>>>(h2o_w, h2oa, h2oz, C_);
  conv_swish_k<<<(C_*H_ + 255)/256, 256, 0, stream>>>(embed_w, swe, C_*H_);
  hipMemsetAsync(cbuf, 0, B_ * sizeof(int), stream);        // c0 = SOS = 0

  // h0 = z @ z2h_w^T + b  -> h1a and h2a
  gemm_bt<2><<<dim3(H_/128, B_/128), 256, 0, stream>>>(zb, L_, z2hb, L_, z2h_b, h1a, h2a, H_, L_);
  // E_gi[c] = swish(embed)[c] @ w_ih0[:, :H]^T + b_ih0   (bf16)
  gemm_bt<1><<<dim3(H3_/128, 1), 256, 0, stream>>>(swe, H_, wih0a, H_, b_ih0, EgiB, nullptr, H3_, H_);
  // Gz = z @ w_ih0[:, H:]^T  (loop-invariant)
  gemm_bt<1><<<dim3(H3_/128, B_/128), 256, 0, stream>>>(zb, L_, wih0z, L_, nullptr, Gz, nullptr, H3_, L_);
  // Oz = z @ h2o_w[:, H:]^T + h2o_b  (loop-invariant)
  gemm_bt<0><<<dim3(1, B_/128), 256, 0, stream>>>(zb, L_, h2oz, L_, h2o_b, Oz, nullptr, C_, L_);

  // ---- 64 sequential decode steps: 3 dispatches each ----
  for (int t = 0; t < T_; t++) {
    const u16* h2cur = (t & 1) ? h2b : h2a;
    u16*       h2nxt = (t & 1) ? h2a : h2b;
    const u16* h1cur = (t & 1) ? h1b : h1a;
    u16*       h1nxt = (t & 1) ? h1a : h1b;
    if (t > 0)
      out_k<<<64, 256, 0, stream>>>(h2cur, h2oa, Oz, outp, cbuf, t - 1);
    gru0_256<<<256, 512, 0, stream>>>(h1cur, whh0, b_hh0, cbuf, EgiB, Gz, h1nxt);
    gru1_256<<<256, 512, 0, stream>>>(h1nxt, h2cur, wih1, whh1, b_ih1, b_hh1, h2nxt);
  }
  // final logits/argmax for t = 63 (h2 state lives in h2a after t=63)
  out_k<<<64, 256, 0, stream>>>(h2a, h2oa, Oz, outp, cbuf, T_ - 1);
}

// Round 8
// 6773.210 us; speedup vs baseline: 1.0284x; 1.0284x over previous
//
#include <hip/hip_runtime.h>
#include <hip/hip_bf16.h>
#include <stdint.h>
#include <stddef.h>

// Problem constants
#define B_   4096
#define H_   1024
#define L_   256
#define C_   128
#define T_   64
#define H3_  3072

typedef unsigned short u16;
typedef __attribute__((ext_vector_type(8))) short bf16x8;   // 8 bf16 = 4 VGPRs
typedef __attribute__((ext_vector_type(4))) float f32x4;

typedef const void __attribute__((address_space(1)))* as1_cvp;
typedef void __attribute__((address_space(3)))* as3_vp;

__device__ __forceinline__ void gl2lds16(const void* g, void* l) {
  __builtin_amdgcn_global_load_lds((as1_cvp)g, (as3_vp)l, 16, 0, 0);
}

__device__ __forceinline__ float bf2f(u16 u) {
  union { float f; unsigned int i; } x; x.i = ((unsigned int)u) << 16; return x.f;
}
__device__ __forceinline__ u16 f2bf(float f) {
  union { float f; unsigned int i; } x; x.f = f;
  unsigned int r = x.i + 0x7fffu + ((x.i >> 16) & 1u);  // RNE
  return (u16)(r >> 16);
}
__device__ __forceinline__ float sigm(float x) { return 1.f / (1.f + __expf(-x)); }
__device__ __forceinline__ float tanh_fast(float x) {
  float e = __expf(2.f * x); return 1.f - 2.f / (e + 1.f);
}

// ===========================================================================
// FULL-XOR LDS SWIZZLE (round 8). Rows are 64 bf16 = 128B = 8x16B slots.
// Invariant: LDS slot s of row r holds GLOBAL 16B-chunk (s ^ (r&7)).
//  - Staging (gl2lds16, linear dest lane*16B): lane covers row base+(lane>>3),
//    slot lane&7 -> global chunk offset = ((lane&7) ^ (lane>>3)) * 16B.
//    (All row-block offsets in stage helpers are multiples of 8 rows, so
//    row&7 == lane>>3 everywhere.)
//  - Reads: global chunk g of row r is at slot g ^ (r&7).
// Per quarter-wave (fixed lq) 16 rows spread over all 8 slots -> 2-way (free)
// vs the old 1-bit swizzle's 8-way (half the LDS BW — the measured ~37%
// MfmaUtil plateau and R3's 5.2M bank-conflict count).
// ===========================================================================
__device__ __forceinline__ int stage_swz(int lane) {
  return ((lane & 7) ^ (lane >> 3)) << 3;   // u16 units
}

// ---------------------------------------------------------------------------
// 128x128-tile bf16 GEMM body (m97 structure) — per-call precompute GEMMs only.
// Now with the full-XOR swizzle pair.
// ---------------------------------------------------------------------------
template<int OUT_MODE>
__device__ __forceinline__ void gemm_tile_body(
    u16* As, u16* Ws,
    const u16* __restrict__ A, int lda,
    const u16* __restrict__ W, int ldw,
    const float* __restrict__ bias,
    void* __restrict__ C0p, void* __restrict__ C1p, int ldc, int K,
    int m0, int n0)
{
  const int tid  = threadIdx.x;
  const int wave = tid >> 6, lane = tid & 63;
  const int wm = (wave >> 1) * 64, wn = (wave & 1) * 64;
  const int lrow = lane & 15, lq = lane >> 4;
  const int arow = wave * 8 + (lane >> 3);
  const int acol = stage_swz(lane);
  const int sb = (lq ^ (lrow & 7)) << 3;    // read slot for kk=0 (u16)

  f32x4 acc[4][4] = {};

  const u16* Ag = A + (size_t)m0 * lda;
  const u16* Wg = W + (size_t)n0 * ldw;

  for (int k0 = 0; k0 < K; k0 += 64) {
    __syncthreads();
    #pragma unroll
    for (int rd = 0; rd < 4; rd++) {
      gl2lds16(Ag + (size_t)(rd * 32 + arow) * lda + (k0 + acol), As + rd * 2048 + wave * 512);
      gl2lds16(Wg + (size_t)(rd * 32 + arow) * ldw + (k0 + acol), Ws + rd * 2048 + wave * 512);
    }
    __syncthreads();
    #pragma unroll
    for (int kk = 0; kk < 64; kk += 32) {
      const int c = (kk == 0) ? sb : (sb ^ 32);
      bf16x8 af[4], bw[4];
      #pragma unroll
      for (int i = 0; i < 4; i++)
        af[i] = *(const bf16x8*)&As[(wm + i * 16 + lrow) * 64 + c];
      #pragma unroll
      for (int j = 0; j < 4; j++)
        bw[j] = *(const bf16x8*)&Ws[(wn + j * 16 + lrow) * 64 + c];
      #pragma unroll
      for (int i = 0; i < 4; i++)
        #pragma unroll
        for (int j = 0; j < 4; j++)
          acc[i][j] = __builtin_amdgcn_mfma_f32_16x16x32_bf16(af[i], bw[j], acc[i][j], 0, 0, 0);
    }
  }

  #pragma unroll
  for (int j = 0; j < 4; j++) {
    const int col = n0 + wn + j * 16 + lrow;
    const float bv = bias ? bias[col] : 0.f;
    #pragma unroll
    for (int i = 0; i < 4; i++) {
      #pragma unroll
      for (int r = 0; r < 4; r++) {
        const int row = m0 + wm + i * 16 + lq * 4 + r;
        float v = acc[i][j][r] + bv;
        if (OUT_MODE == 0) {
          ((float*)C0p)[(size_t)row * ldc + col] = v;
        } else if (OUT_MODE == 1) {
          ((u16*)C0p)[(size_t)row * ldc + col] = f2bf(v);
        } else {
          u16 hv = f2bf(v);
          ((u16*)C0p)[(size_t)row * ldc + col] = hv;
          ((u16*)C1p)[(size_t)row * ldc + col] = hv;
        }
      }
    }
  }
}

template<int OUT_MODE>
__global__ __launch_bounds__(256) void gemm_bt(
    const u16* __restrict__ A, int lda,
    const u16* __restrict__ W, int ldw,
    const float* __restrict__ bias,
    void* __restrict__ C0p, void* __restrict__ C1p, int ldc, int K)
{
  __shared__ __align__(16) u16 As[128 * 64];
  __shared__ __align__(16) u16 Ws[128 * 64];
  gemm_tile_body<OUT_MODE>(As, Ws, A, lda, W, ldw, bias, C0p, C1p, ldc, K,
                           blockIdx.y * 128, blockIdx.x * 128);
}

// ---------------------------------------------------------------------------
// out = h2 @ Wo^T + Oz; writes d_out[:,t,:], per-row argmax -> cnew.
// 2-deep counted-vmcnt pipeline (round 6) + full-XOR swizzle (round 8).
// ---------------------------------------------------------------------------
#define OA_TSZ 4096   // 64x64 u16
#define OW_TSZ 8192   // 128x64 u16

__device__ __forceinline__ void o_stage(const u16* h2, const u16* Wo,
                                        int b0, int k0, u16* bA, u16* bW) {
  const int tid = threadIdx.x, wave = tid >> 6, lane = tid & 63;
  const int arow = wave * 8 + (lane >> 3);
  const int cSw = stage_swz(lane);
  #pragma unroll
  for (int rd = 0; rd < 2; rd++)
    gl2lds16(h2 + (size_t)(b0 + rd * 32 + arow) * H_ + k0 + cSw, bA + rd * 2048 + wave * 512);
  #pragma unroll
  for (int rd = 0; rd < 4; rd++)
    gl2lds16(Wo + (size_t)(rd * 32 + arow) * H_ + k0 + cSw, bW + rd * 2048 + wave * 512);
}

__device__ __forceinline__ void out_body(
    u16* As, u16* Ws, int ob,
    const u16* __restrict__ h2, const u16* __restrict__ Wo,
    const float* __restrict__ Oz, float* __restrict__ outp,
    int* __restrict__ cnew, int t)
{
  const int tid = threadIdx.x, wave = tid >> 6, lane = tid & 63;
  const int b0 = ob * 64;
  const int lrow = lane & 15, lq = lane >> 4;
  const int sb = (lq ^ (lrow & 7)) << 3;
  f32x4 acc[8] = {};

  o_stage(h2, Wo, b0, 0, As, Ws);
  o_stage(h2, Wo, b0, 64, As + OA_TSZ, Ws + OW_TSZ);

  #pragma unroll 1
  for (int v = 0; v < 16; v++) {
    u16* bA = (v & 1) ? As + OA_TSZ : As;
    u16* bW = (v & 1) ? Ws + OW_TSZ : Ws;
    if (v + 1 < 16) asm volatile("s_waitcnt vmcnt(6)" ::: "memory");
    else            asm volatile("s_waitcnt vmcnt(0)" ::: "memory");
    __builtin_amdgcn_sched_barrier(0);
    __builtin_amdgcn_s_barrier();
    __builtin_amdgcn_sched_barrier(0);
    #pragma unroll
    for (int kk = 0; kk < 64; kk += 32) {
      const int c = (kk == 0) ? sb : (sb ^ 32);
      bf16x8 af = *(const bf16x8*)&bA[(wave * 16 + lrow) * 64 + c];
      #pragma unroll
      for (int j = 0; j < 8; j++) {
        bf16x8 bw = *(const bf16x8*)&bW[(j * 16 + lrow) * 64 + c];
        acc[j] = __builtin_amdgcn_mfma_f32_16x16x32_bf16(af, bw, acc[j], 0, 0, 0);
      }
    }
    __builtin_amdgcn_sched_barrier(0);
    __builtin_amdgcn_s_barrier();
    __builtin_amdgcn_sched_barrier(0);
    if (v + 2 < 16) o_stage(h2, Wo, b0, (v + 2) * 64, bA, bW);
  }

  #pragma unroll
  for (int r = 0; r < 4; r++) {
    const int row = b0 + wave * 16 + lq * 4 + r;
    float mv = -3.4e38f; int mi = 0;
    #pragma unroll
    for (int j = 0; j < 8; j++) {
      const int col = j * 16 + lrow;
      float v = acc[j][r] + Oz[(size_t)row * C_ + col];
      outp[(size_t)row * (T_ * C_) + t * C_ + col] = v;
      if (v > mv) { mv = v; mi = col; }
    }
    #pragma unroll
    for (int off = 1; off < 16; off <<= 1) {
      float ov = __shfl_xor(mv, off);
      int   oi = __shfl_xor(mi, off);
      if (ov > mv || (ov == mv && oi < mi)) { mv = ov; mi = oi; }
    }
    if (lrow == 0) cnew[row] = mi;
  }
}

__global__ __launch_bounds__(256) void out_k(
    const u16* __restrict__ h2cur, const u16* __restrict__ Wo,
    const float* __restrict__ Oz, float* __restrict__ outp,
    int* __restrict__ cbuf, int t)
{
  __shared__ __align__(16) u16 As[2 * OA_TSZ];
  __shared__ __align__(16) u16 Ws[2 * OW_TSZ];
  out_body(As, Ws, blockIdx.x, h2cur, Wo, Oz, outp, cbuf, t);
}

// ===========================================================================
// 256-row x 64-j x 3-gate fused GRU GEMM — round-6 phase schedule (proven
// best) + round-8 full-XOR swizzle. 3 phases/tile, per-phase {ds_read ||
// stage || lgkmcnt(0) || setprio || MFMA || barrier}; A 3-deep, W 2-deep,
// head vmcnt(4); MFMA phase variant compile-time.
// ===========================================================================

#define A_TSZ 16384   // 256x64 u16
#define W_TSZ 12288   // 192x64 u16

__device__ __forceinline__ void stageA_lo(const u16* Ag, int k0, u16* bA) {
  const int tid = threadIdx.x, wave = tid >> 6, lane = tid & 63;
  const int r64 = wave * 8 + (lane >> 3);
  const int cSw = stage_swz(lane);
  gl2lds16(Ag + (size_t)(r64) * H_ + k0 + cSw, bA + wave * 512);
  gl2lds16(Ag + (size_t)(64 + r64) * H_ + k0 + cSw, bA + 4096 + wave * 512);
}
__device__ __forceinline__ void stageA_hi(const u16* Ag, int k0, u16* bA) {
  const int tid = threadIdx.x, wave = tid >> 6, lane = tid & 63;
  const int r64 = wave * 8 + (lane >> 3);
  const int cSw = stage_swz(lane);
  gl2lds16(Ag + (size_t)(128 + r64) * H_ + k0 + cSw, bA + 8192 + wave * 512);
  gl2lds16(Ag + (size_t)(192 + r64) * H_ + k0 + cSw, bA + 12288 + wave * 512);
}
__device__ __forceinline__ void stageW(const u16* Wg, int k0, u16* bW) {
  const int tid = threadIdx.x, wave = tid >> 6, lane = tid & 63;
  const int r64 = wave * 8 + (lane >> 3);
  const int cSw = stage_swz(lane);
  #pragma unroll
  for (int rd = 0; rd < 3; rd++)
    gl2lds16(Wg + (size_t)(rd * 1024 + r64) * H_ + k0 + cSw, bW + rd * 4096 + wave * 512);
}

// Phase p reads (LDS -> regs). Phase MFMA groups (16 each):
//   P0: {g0,g1}@kk0   P1: {g2}@kk0 + {g0}@kk32   P2: {g1,g2}@kk32
template<int PHASE>
__device__ __forceinline__ void phase_reads(const u16* bA, const u16* bW,
    bf16x8 af0[4], bf16x8 af1[4], bf16x8 bwv[2][2])
{
  const int tid = threadIdx.x, wave = tid >> 6, lane = tid & 63;
  const int wmh = wave >> 1, wj = wave & 1;
  const int lrow = lane & 15, lq = lane >> 4;
  const int sb = (lq ^ (lrow & 7)) << 3;
  const int c0 = sb;        // kk=0 chunk
  const int c1 = sb ^ 32;   // kk=32 chunk (slot^4)
  if (PHASE == 0) {
    #pragma unroll
    for (int i = 0; i < 4; i++)
      af0[i] = *(const bf16x8*)&bA[(wmh * 64 + i * 16 + lrow) * 64 + c0];
    #pragma unroll
    for (int u = 0; u < 2; u++) {
      bwv[0][u] = *(const bf16x8*)&bW[(wj * 32 + u * 16 + lrow) * 64 + c0];
      bwv[1][u] = *(const bf16x8*)&bW[(64 + wj * 32 + u * 16 + lrow) * 64 + c0];
    }
  } else if (PHASE == 1) {
    #pragma unroll
    for (int i = 0; i < 4; i++)
      af1[i] = *(const bf16x8*)&bA[(wmh * 64 + i * 16 + lrow) * 64 + c1];
    #pragma unroll
    for (int u = 0; u < 2; u++) {
      bwv[0][u] = *(const bf16x8*)&bW[(128 + wj * 32 + u * 16 + lrow) * 64 + c0];
      bwv[1][u] = *(const bf16x8*)&bW[(wj * 32 + u * 16 + lrow) * 64 + c1];
    }
  } else {
    #pragma unroll
    for (int u = 0; u < 2; u++) {
      bwv[0][u] = *(const bf16x8*)&bW[(64 + wj * 32 + u * 16 + lrow) * 64 + c1];
      bwv[1][u] = *(const bf16x8*)&bW[(128 + wj * 32 + u * 16 + lrow) * 64 + c1];
    }
  }
}

template<int PHASE, bool PH2v>
__device__ __forceinline__ void phase_fma(const bf16x8 bwv[2][2],
    const bf16x8 af0[4], const bf16x8 af1[4],
    f32x4 acc[3][2][4], f32x4 accN[2][4])
{
  if (PHASE == 0) {
    #pragma unroll
    for (int u = 0; u < 2; u++)
      #pragma unroll
      for (int i = 0; i < 4; i++) {
        acc[0][u][i] = __builtin_amdgcn_mfma_f32_16x16x32_bf16(af0[i], bwv[0][u], acc[0][u][i], 0, 0, 0);
        acc[1][u][i] = __builtin_amdgcn_mfma_f32_16x16x32_bf16(af0[i], bwv[1][u], acc[1][u][i], 0, 0, 0);
      }
  } else if (PHASE == 1) {
    #pragma unroll
    for (int u = 0; u < 2; u++)
      #pragma unroll
      for (int i = 0; i < 4; i++) {
        if (PH2v)
          accN[u][i] = __builtin_amdgcn_mfma_f32_16x16x32_bf16(af0[i], bwv[0][u], accN[u][i], 0, 0, 0);
        else
          acc[2][u][i] = __builtin_amdgcn_mfma_f32_16x16x32_bf16(af0[i], bwv[0][u], acc[2][u][i], 0, 0, 0);
        acc[0][u][i] = __builtin_amdgcn_mfma_f32_16x16x32_bf16(af1[i], bwv[1][u], acc[0][u][i], 0, 0, 0);
      }
  } else {
    #pragma unroll
    for (int u = 0; u < 2; u++)
      #pragma unroll
      for (int i = 0; i < 4; i++) {
        acc[1][u][i] = __builtin_amdgcn_mfma_f32_16x16x32_bf16(af1[i], bwv[0][u], acc[1][u][i], 0, 0, 0);
        if (PH2v)
          accN[u][i] = __builtin_amdgcn_mfma_f32_16x16x32_bf16(af1[i], bwv[1][u], accN[u][i], 0, 0, 0);
        else
          acc[2][u][i] = __builtin_amdgcn_mfma_f32_16x16x32_bf16(af1[i], bwv[1][u], acc[2][u][i], 0, 0, 0);
      }
  }
}

// One 64-K tile: head wait+barrier, then 3 interleaved phases (R6 structure).
template<int NT1, int NT2, bool PH2v>
__device__ __forceinline__ void tile8(
    int v, u16* aC, u16* wC, u16* wN, u16* aN2,
    const u16* A1g, const u16* W1g, const u16* A2g, const u16* W2g,
    f32x4 acc[3][2][4], f32x4 accN[2][4])
{
  constexpr int NT = NT1 + NT2;
  if (v + 1 < NT) asm volatile("s_waitcnt vmcnt(4)" ::: "memory");
  else            asm volatile("s_waitcnt vmcnt(0)" ::: "memory");
  __builtin_amdgcn_sched_barrier(0);
  __builtin_amdgcn_s_barrier();
  __builtin_amdgcn_sched_barrier(0);

  bf16x8 af0[4], af1[4], bwv[2][2];

  // ---- P0 ----
  phase_reads<0>(aC, wC, af0, af1, bwv);
  {
    const int w = v + 1;
    if (w < NT) stageW((w < NT1) ? W1g : W2g, ((w < NT1) ? w : w - NT1) * 64, wN);
  }
  asm volatile("s_waitcnt lgkmcnt(0)" ::: "memory");
  __builtin_amdgcn_sched_barrier(0);
  __builtin_amdgcn_s_setprio(1);
  phase_fma<0, PH2v>(bwv, af0, af1, acc, accN);
  __builtin_amdgcn_s_setprio(0);
  __builtin_amdgcn_sched_barrier(0);
  __builtin_amdgcn_s_barrier();
  __builtin_amdgcn_sched_barrier(0);

  // ---- P1 ----
  phase_reads<1>(aC, wC, af0, af1, bwv);
  {
    const int w = v + 2;
    if (w < NT) stageA_lo((w < NT1) ? A1g : A2g, ((w < NT1) ? w : w - NT1) * 64, aN2);
  }
  asm volatile("s_waitcnt lgkmcnt(0)" ::: "memory");
  __builtin_amdgcn_sched_barrier(0);
  __builtin_amdgcn_s_setprio(1);
  phase_fma<1, PH2v>(bwv, af0, af1, acc, accN);
  __builtin_amdgcn_s_setprio(0);
  __builtin_amdgcn_sched_barrier(0);
  __builtin_amdgcn_s_barrier();
  __builtin_amdgcn_sched_barrier(0);

  // ---- P2 ----
  phase_reads<2>(aC, wC, af0, af1, bwv);
  {
    const int w = v + 2;
    if (w < NT) stageA_hi((w < NT1) ? A1g : A2g, ((w < NT1) ? w : w - NT1) * 64, aN2);
  }
  asm volatile("s_waitcnt lgkmcnt(0)" ::: "memory");
  __builtin_amdgcn_sched_barrier(0);
  __builtin_amdgcn_s_setprio(1);
  phase_fma<2, PH2v>(bwv, af0, af1, acc, accN);
  __builtin_amdgcn_s_setprio(0);
  __builtin_amdgcn_sched_barrier(0);
}

template<int NT1, int NT2>
__device__ __forceinline__ void kloop8(
    u16* As, u16* Ws,
    const u16* A1g, const u16* W1g, const u16* A2g, const u16* W2g,
    f32x4 acc[3][2][4], f32x4 accN[2][4])
{
  constexpr int NT = NT1 + NT2;
  u16* aB0 = As; u16* aB1 = As + A_TSZ; u16* aB2 = As + 2 * A_TSZ;
  u16* wB0 = Ws; u16* wB1 = Ws + W_TSZ;

  // prologue issue order matters for vmcnt: A(0) [4], W(0) [3], A(1) [4]
  stageA_lo(A1g, 0, aB0); stageA_hi(A1g, 0, aB0);
  stageW(W1g, 0, wB0);
  if (NT > 1) {
    const u16* Ag = (1 < NT1) ? A1g : A2g;
    const int k0 = (1 < NT1) ? 64 : 0;
    stageA_lo(Ag, k0, aB1); stageA_hi(Ag, k0, aB1);
  }

  u16* aC = aB0; u16* aN1 = aB1; u16* aN2 = aB2;
  u16* wC = wB0; u16* wN = wB1;

  #pragma unroll 1
  for (int v = 0; v < NT1; v++) {
    tile8<NT1, NT2, false>(v, aC, wC, wN, aN2, A1g, W1g, A2g, W2g, acc, accN);
    u16* t = aC; aC = aN1; aN1 = aN2; aN2 = t;
    u16* tw = wC; wC = wN; wN = tw;
  }
  #pragma unroll 1
  for (int v = NT1; v < NT; v++) {
    tile8<NT1, NT2, true>(v, aC, wC, wN, aN2, A1g, W1g, A2g, W2g, acc, accN);
    u16* t = aC; aC = aN1; aN1 = aN2; aN2 = t;
    u16* tw = wC; wC = wN; wN = tw;
  }
}

// Layer-0 fused: gh0 GEMM + GRU cell0 epilogue (Egi gather + Gz + h1 update).
__global__ __launch_bounds__(512, 2) void gru0_256(
    const u16* __restrict__ h1old, const u16* __restrict__ whh0,
    const float* __restrict__ b_hh0, const int* __restrict__ cbuf,
    const u16* __restrict__ Egi, const u16* __restrict__ Gz,
    u16* __restrict__ h1new)
{
  __shared__ __align__(16) u16 As[3 * A_TSZ];
  __shared__ __align__(16) u16 Ws[2 * W_TSZ];
  const int bid = blockIdx.x;
  const int xcd = bid & 7, k = bid >> 3;   // k: 0..31
  const int jt = xcd * 2 + (k & 1);        // 0..15
  const int m  = k >> 1;                   // 0..15
  const int m0 = m * 256, j0 = jt * 64;

  f32x4 acc[3][2][4] = {};
  f32x4 accN[2][4] = {};
  kloop8<16, 0>(As, Ws,
                h1old + (size_t)m0 * H_, whh0 + (size_t)j0 * H_,
                h1old + (size_t)m0 * H_, whh0 + (size_t)j0 * H_,
                acc, accN);

  const int tid = threadIdx.x, wave = tid >> 6, lane = tid & 63;
  const int wmh = wave >> 1, wj = wave & 1;
  const int lrow = lane & 15, lq = lane >> 4;

  #pragma unroll
  for (int u = 0; u < 2; u++) {
    const int j = j0 + wj * 32 + u * 16 + lrow;
    const float bR = b_hh0[j];
    const float bZ = b_hh0[H_ + j];
    const float bN = b_hh0[2 * H_ + j];
    #pragma unroll
    for (int i = 0; i < 4; i++) {
      #pragma unroll
      for (int rr = 0; rr < 4; rr++) {
        const int row = m0 + wmh * 64 + i * 16 + lq * 4 + rr;
        const size_t eb = (size_t)cbuf[row] * H3_ + j;
        const size_t gb = (size_t)row * H3_ + j;
        float r  = sigm(bf2f(Egi[eb])           + bf2f(Gz[gb])           + acc[0][u][i][rr] + bR);
        float zg = sigm(bf2f(Egi[eb + H_])      + bf2f(Gz[gb + H_])      + acc[1][u][i][rr] + bZ);
        float nn = tanh_fast(bf2f(Egi[eb + 2 * H_]) + bf2f(Gz[gb + 2 * H_])
                             + r * (acc[2][u][i][rr] + bN));
        float hold = bf2f(h1old[(size_t)row * H_ + j]);
        h1new[(size_t)row * H_ + j] = f2bf((1.f - zg) * nn + zg * hold);
      }
    }
  }
}

// Layer-1 fused: dual GEMM (gi1 = h1@wih1^T tiles 0..15, gh1 = h2old@whh1^T
// tiles 16..31; r/z shared accumulators, n separate) + GRU cell1 -> h2new.
__global__ __launch_bounds__(512, 2) void gru1_256(
    const u16* __restrict__ h1, const u16* __restrict__ h2old,
    const u16* __restrict__ wih1, const u16* __restrict__ whh1,
    const float* __restrict__ b_ih1, const float* __restrict__ b_hh1,
    u16* __restrict__ h2new)
{
  __shared__ __align__(16) u16 As[3 * A_TSZ];
  __shared__ __align__(16) u16 Ws[2 * W_TSZ];
  const int bid = blockIdx.x;
  const int xcd = bid & 7, k = bid >> 3;
  const int jt = xcd * 2 + (k & 1);
  const int m  = k >> 1;
  const int m0 = m * 256, j0 = jt * 64;

  f32x4 acc[3][2][4] = {};
  f32x4 accN[2][4] = {};
  kloop8<16, 16>(As, Ws,
                 h1    + (size_t)m0 * H_, wih1 + (size_t)j0 * H_,
                 h2old + (size_t)m0 * H_, whh1 + (size_t)j0 * H_,
                 acc, accN);

  const int tid = threadIdx.x, wave = tid >> 6, lane = tid & 63;
  const int wmh = wave >> 1, wj = wave & 1;
  const int lrow = lane & 15, lq = lane >> 4;

  #pragma unroll
  for (int u = 0; u < 2; u++) {
    const int j = j0 + wj * 32 + u * 16 + lrow;
    const float bR  = b_ih1[j] + b_hh1[j];
    const float bZ  = b_ih1[H_ + j] + b_hh1[H_ + j];
    const float bNi = b_ih1[2 * H_ + j];
    const float bNh = b_hh1[2 * H_ + j];
    #pragma unroll
    for (int i = 0; i < 4; i++) {
      #pragma unroll
      for (int rr = 0; rr < 4; rr++) {
        const int row = m0 + wmh * 64 + i * 16 + lq * 4 + rr;
        float r  = sigm(acc[0][u][i][rr] + bR);
        float zg = sigm(acc[1][u][i][rr] + bZ);
        float nn = tanh_fast(acc[2][u][i][rr] + bNi + r * (accN[u][i][rr] + bNh));
        float hold = bf2f(h2old[(size_t)row * H_ + j]);
        h2new[(size_t)row * H_ + j] = f2bf((1.f - zg) * nn + zg * hold);
      }
    }
  }
}

// --------------------------- conversion kernels ----------------------------
__global__ __launch_bounds__(256) void conv_bf16_k(const float* __restrict__ s, u16* __restrict__ d, int n) {
  int i = blockIdx.x * 256 + threadIdx.x;
  if (i < n) d[i] = f2bf(s[i]);
}
__global__ __launch_bounds__(256) void conv_split_k(const float* __restrict__ s, u16* __restrict__ dA,
                                                    u16* __restrict__ dZ, int rows) {
  int i = blockIdx.x * 256 + threadIdx.x;
  if (i >= rows * 1280) return;
  int rr = i / 1280, col = i - rr * 1280;
  float v = s[i];
  if (col < 1024) dA[(size_t)rr * 1024 + col] = f2bf(v);
  else            dZ[(size_t)rr * 256 + (col - 1024)] = f2bf(v);
}
__global__ __launch_bounds__(256) void conv_swish_k(const float* __restrict__ s, u16* __restrict__ d, int n) {
  int i = blockIdx.x * 256 + threadIdx.x;
  if (i < n) { float e = s[i]; d[i] = f2bf(e * sigm(e)); }
}

// ---------------------------------------------------------------------------
static inline char* wsal(char*& p, size_t bytes) {
  char* r = p; p += (bytes + 255) & ~(size_t)255; return r;
}

extern "C" void kernel_launch(void* const* d_in, const int* in_sizes, int n_in,
                              void* d_out, int out_size, void* d_ws, size_t ws_size,
                              hipStream_t stream) {
  const float* z       = (const float*)d_in[0];
  const float* embed_w = (const float*)d_in[1];
  const float* z2h_w   = (const float*)d_in[2];
  const float* z2h_b   = (const float*)d_in[3];
  const float* w_ih0   = (const float*)d_in[4];
  const float* w_hh0   = (const float*)d_in[5];
  const float* b_ih0   = (const float*)d_in[6];
  const float* b_hh0   = (const float*)d_in[7];
  const float* w_ih1   = (const float*)d_in[8];
  const float* w_hh1   = (const float*)d_in[9];
  const float* b_ih1   = (const float*)d_in[10];
  const float* b_hh1   = (const float*)d_in[11];
  const float* h2o_w   = (const float*)d_in[12];
  const float* h2o_b   = (const float*)d_in[13];
  float* outp = (float*)d_out;

  char* p = (char*)d_ws;
  u16* whh0  = (u16*)wsal(p, (size_t)H3_ * H_ * 2);
  u16* wih1  = (u16*)wsal(p, (size_t)H3_ * H_ * 2);
  u16* whh1  = (u16*)wsal(p, (size_t)H3_ * H_ * 2);
  u16* wih0a = (u16*)wsal(p, (size_t)H3_ * H_ * 2);
  u16* wih0z = (u16*)wsal(p, (size_t)H3_ * L_ * 2);
  u16* h2oa  = (u16*)wsal(p, (size_t)C_ * H_ * 2);
  u16* h2oz  = (u16*)wsal(p, (size_t)C_ * L_ * 2);
  u16* z2hb  = (u16*)wsal(p, (size_t)H_ * L_ * 2);
  u16* zb    = (u16*)wsal(p, (size_t)B_ * L_ * 2);
  u16* swe   = (u16*)wsal(p, (size_t)C_ * H_ * 2);
  u16* EgiB  = (u16*)wsal(p, (size_t)C_ * H3_ * 2);
  u16* Gz    = (u16*)wsal(p, (size_t)B_ * H3_ * 2);
  float* Oz  = (float*)wsal(p, (size_t)B_ * C_ * 4);
  u16* h1a   = (u16*)wsal(p, (size_t)B_ * H_ * 2);
  u16* h1b   = (u16*)wsal(p, (size_t)B_ * H_ * 2);
  u16* h2a   = (u16*)wsal(p, (size_t)B_ * H_ * 2);
  u16* h2b   = (u16*)wsal(p, (size_t)B_ * H_ * 2);
  int* cbuf  = (int*)wsal(p, (size_t)B_ * 4);

  // ---- one-time (per call) precompute ----
  conv_bf16_k<<<(B_*L_ + 255)/256, 256, 0, stream>>>(z, zb, B_*L_);
  conv_bf16_k<<<(H_*L_ + 255)/256, 256, 0, stream>>>(z2h_w, z2hb, H_*L_);
  conv_bf16_k<<<(H3_*H_ + 255)/256, 256, 0, stream>>>(w_hh0, whh0, H3_*H_);
  conv_bf16_k<<<(H3_*H_ + 255)/256, 256, 0, stream>>>(w_ih1, wih1, H3_*H_);
  conv_bf16_k<<<(H3_*H_ + 255)/256, 256, 0, stream>>>(w_hh1, whh1, H3_*H_);
  conv_split_k<<<(H3_*1280 + 255)/256, 256, 0, stream>>>(w_ih0, wih0a, wih0z, H3_);
  conv_split_k<<<(C_*1280 + 255)/256, 256, 0, stream>>>(h2o_w, h2oa, h2oz, C_);
  conv_swish_k<<<(C_*H_ + 255)/256, 256, 0, stream>>>(embed_w, swe, C_*H_);
  hipMemsetAsync(cbuf, 0, B_ * sizeof(int), stream);        // c0 = SOS = 0

  // h0 = z @ z2h_w^T + b  -> h1a and h2a
  gemm_bt<2><<<dim3(H_/128, B_/128), 256, 0, stream>>>(zb, L_, z2hb, L_, z2h_b, h1a, h2a, H_, L_);
  // E_gi[c] = swish(embed)[c] @ w_ih0[:, :H]^T + b_ih0   (bf16)
  gemm_bt<1><<<dim3(H3_/128, 1), 256, 0, stream>>>(swe, H_, wih0a, H_, b_ih0, EgiB, nullptr, H3_, H_);
  // Gz = z @ w_ih0[:, H:]^T  (loop-invariant)
  gemm_bt<1><<<dim3(H3_/128, B_/128), 256, 0, stream>>>(zb, L_, wih0z, L_, nullptr, Gz, nullptr, H3_, L_);
  // Oz = z @ h2o_w[:, H:]^T + h2o_b  (loop-invariant)
  gemm_bt<0><<<dim3(1, B_/128), 256, 0, stream>>>(zb, L_, h2oz, L_, h2o_b, Oz, nullptr, C_, L_);

  // ---- 64 sequential decode steps: 3 dispatches each ----
  for (int t = 0; t < T_; t++) {
    const u16* h2cur = (t & 1) ? h2b : h2a;
    u16*       h2nxt = (t & 1) ? h2a : h2b;
    const u16* h1cur = (t & 1) ? h1b : h1a;
    u16*       h1nxt = (t & 1) ? h1a : h1b;
    if (t > 0)
      out_k<<<64, 256, 0, stream>>>(h2cur, h2oa, Oz, outp, cbuf, t - 1);
    gru0_256<<<256, 512, 0, stream>>>(h1cur, whh0, b_hh0, cbuf, EgiB, Gz, h1nxt);
    gru1_256<<<256, 512, 0, stream>>>(h1nxt, h2cur, wih1, whh1, b_ih1, b_hh1, h2nxt);
  }
  // final logits/argmax for t = 63 (h2 state lives in h2a after t=63)
  out_k<<<64, 256, 0, stream>>>(h2a, h2oa, Oz, outp, cbuf, T_ - 1);
}